// Round 3
// baseline (983.540 us; speedup 1.0000x reference)
//
#include <hip/hip_runtime.h>
#include <hip/hip_bf16.h>
#include <math.h>

#define TT 512
#define NN 200
#define HH 64
#define EE 16
#define RR 10
#define MU_OFF 0
#define COV_OFF (TT*NN)      // 102400
#define HBLK (NN*NN)         // 40000 floats per t-block of cov
#define HPAD 68              // padded hist row (68%32=4 spreads banks per step-row)

__device__ __forceinline__ float sigmoidf_(float x) {
    return 1.0f / (1.0f + __expf(-x));
}
__device__ __forceinline__ float tanhf_(float x) {
    x = fminf(15.0f, fmaxf(-15.0f, x));
    float e = __expf(2.0f * x);
    return (e - 1.0f) / (e + 1.0f);
}

// ---------------- Kernel A: 2-layer LSTM, layer-pipelined, 1 WG per batch ---
// 768 threads = 3 groups x 256. Every thread holds exactly ONE 64-float
// weight row in registers (no group needs 128 -> nothing spills).
//   grp0 (waves 0-3):  layer0 gates, step t     (Whh0 row + Wih0 scalar)
//   grp1 (waves 4-7):  layer1 ih-partial, t-1   (Wih1 row . h0[t-1])
//   grp2 (waves 8-11): layer1 hh-partial, t-1   (Whh1 row . h1[t-2])
// Update: wave0 -> layer0 c/h;  wave8 -> combine partials, layer1 c/h.
__global__ __launch_bounds__(768, 3) void lstm_kernel(
    const float* __restrict__ inputs,
    const float* __restrict__ Wih0, const float* __restrict__ Whh0,
    const float* __restrict__ bih0, const float* __restrict__ bhh0,
    const float* __restrict__ Wih1, const float* __restrict__ Whh1,
    const float* __restrict__ bih1, const float* __restrict__ bhh1,
    float* __restrict__ out)
{
    const int n   = blockIdx.x;
    const int tid = threadIdx.x;
    const int grp = tid >> 8;       // 0,1,2 (wave-uniform)
    const int r   = tid & 255;      // gate row within group

    __shared__ float xs[TT];
    __shared__ float h0s[HH];
    __shared__ float h1s[HH];
    __shared__ float ga0[256];      // activated layer0 gates
    __shared__ float pih[256];      // layer1 ih partial (incl. bias)
    __shared__ float phh[256];      // layer1 hh partial
    __shared__ float hist[64][HPAD];

    // --- one 64-float weight row per thread, uniform code path -------------
    const float* wsrc = (grp == 0) ? (Whh0 + r * HH)
                       : (grp == 1) ? (Wih1 + r * HH)
                                    : (Whh1 + r * HH);
    float w[HH];
#pragma unroll
    for (int q = 0; q < 16; ++q) {
        float4 a = ((const float4*)wsrc)[q];
        w[4*q+0] = a.x; w[4*q+1] = a.y; w[4*q+2] = a.z; w[4*q+3] = a.w;
    }
    float wx = 0.0f, binit = 0.0f;
    if (grp == 0)      { wx = Wih0[r]; binit = bih0[r] + bhh0[r]; }
    else if (grp == 1) { binit = bih1[r] + bhh1[r]; }
    const int gate = r >> 6;        // wave-uniform

    if (tid < TT) xs[tid] = inputs[tid * NN + n];
    if (tid < HH) { h0s[tid] = 0.0f; h1s[tid] = 0.0f; }
    float c0 = 0.0f, c1 = 0.0f;     // c0 live in wave0, c1 live in wave8
    __syncthreads();

    float* covbase = out + COV_OFF + n * HH;

    for (int t = 0; t <= TT; ++t) {
        // ---- compute phase: three 64-FMA matvecs in parallel -------------
        const bool act = (grp == 0) ? (t < TT) : (t >= 1);
        if (act) {
            const float* src = (grp == 2) ? h1s : h0s;
            float a0 = (grp == 0) ? fmaf(wx, xs[t], binit) : binit;
            float a1 = 0.f, a2 = 0.f, a3 = 0.f;
            const float4* h4 = (const float4*)src;
#pragma unroll
            for (int q = 0; q < 16; ++q) {
                float4 h = h4[q];
                a0 = fmaf(w[4*q+0], h.x, a0);
                a1 = fmaf(w[4*q+1], h.y, a1);
                a2 = fmaf(w[4*q+2], h.z, a2);
                a3 = fmaf(w[4*q+3], h.w, a3);
            }
            float g = (a0 + a1) + (a2 + a3);
            if (grp == 0)      ga0[r] = (gate == 2) ? tanhf_(g) : sigmoidf_(g);
            else if (grp == 1) pih[r] = g;
            else               phh[r] = g;
        }
        __syncthreads();

        // ---- update phase -------------------------------------------------
        if (tid < HH) {
            if (t < TT) {
                float ia = ga0[tid], fa = ga0[tid + 64];
                float gg = ga0[tid + 128], oa = ga0[tid + 192];
                c0 = fmaf(fa, c0, ia * gg);
                h0s[tid] = oa * tanhf_(c0);
            }
        } else if (tid >= 512 && tid < 512 + HH) {
            if (t >= 1) {
                const int j = tid - 512;
                float gi = pih[j]       + phh[j];
                float gf = pih[j + 64]  + phh[j + 64];
                float gg = pih[j + 128] + phh[j + 128];
                float go = pih[j + 192] + phh[j + 192];
                float ia = sigmoidf_(gi), fa = sigmoidf_(gf);
                float ta = tanhf_(gg),    oa = sigmoidf_(go);
                c1 = fmaf(fa, c1, ia * ta);
                float h1 = oa * tanhf_(c1);
                h1s[j] = h1;
                hist[(t - 1) & 63][j] = h1;
            }
        }
        __syncthreads();

        // ---- periodic h1-history flush to global (64 steps at a time) ----
        if ((t & 63) == 0 && t > 0 && tid < 512) {
            const int s = tid >> 3;          // step row 0..63
            const int c = (tid & 7) * 8;     // 8 floats per thread
            float4 v0 = *(const float4*)&hist[s][c];
            float4 v1 = *(const float4*)&hist[s][c + 4];
            float* dst = covbase + (size_t)(t - 64 + s) * HBLK + c;
            ((float4*)dst)[0] = v0;
            ((float4*)dst)[1] = v1;
        }
    }
}

// ---------------- Kernel B: heads + covariance, one workgroup per t ----------
__global__ __launch_bounds__(256) void head_kernel(
    const float* __restrict__ embW, const int* __restrict__ indices,
    const float* __restrict__ Wm, const float* __restrict__ bm,
    const float* __restrict__ Wv, const float* __restrict__ bv,
    const float* __restrict__ Wd, const float* __restrict__ bd,
    float* __restrict__ out)
{
    const int t = blockIdx.x;
    const int tid = threadIdx.x;

    __shared__ float hs[NN * HH];          // 12800
    __shared__ float embs[NN * EE];        // 3200
    __shared__ float Wvs[(HH + EE) * RR];  // 800
    __shared__ float Wms[HH + EE];
    __shared__ float Wds[HH + EE];
    __shared__ float Vs[NN * (RR + 1)];    // stride 11 to dodge bank conflicts
    __shared__ float dsh[NN];
    __shared__ float bvs[RR];

    const float* hsrc = out + COV_OFF + (size_t)t * HBLK;
    for (int i = tid; i < (NN * HH) / 4; i += 256)
        ((float4*)hs)[i] = ((const float4*)hsrc)[i];
    for (int i = tid; i < NN * EE; i += 256) {
        int n = i >> 4, e = i & 15;
        embs[i] = embW[indices[n] * EE + e];
    }
    for (int i = tid; i < (HH + EE) * RR; i += 256) Wvs[i] = Wv[i];
    if (tid < HH + EE) { Wms[tid] = Wm[tid]; Wds[tid] = Wd[tid]; }
    if (tid < RR) bvs[tid] = bv[tid];
    __syncthreads();

    // V = y @ Wv + bv
    for (int p = tid; p < NN * RR; p += 256) {
        int n = p / RR, r = p - n * RR;
        const float* hn = hs + n * HH;
        const float* en = embs + n * EE;
        float acc = bvs[r];
#pragma unroll 8
        for (int k = 0; k < HH; ++k) acc = fmaf(hn[k], Wvs[k * RR + r], acc);
#pragma unroll
        for (int k = 0; k < EE; ++k) acc = fmaf(en[k], Wvs[(HH + k) * RR + r], acc);
        Vs[n * (RR + 1) + r] = acc;
    }
    // mu and d
    const float bmv = bm[0], bdv = bd[0];
    for (int n = tid; n < NN; n += 256) {
        const float* hn = hs + n * HH;
        const float* en = embs + n * EE;
        float am = bmv, ad = bdv;
#pragma unroll 8
        for (int k = 0; k < HH; ++k) {
            float h = hn[k];
            am = fmaf(h, Wms[k], am);
            ad = fmaf(h, Wds[k], ad);
        }
#pragma unroll
        for (int k = 0; k < EE; ++k) {
            float e = en[k];
            am = fmaf(e, Wms[HH + k], am);
            ad = fmaf(e, Wds[HH + k], ad);
        }
        out[MU_OFF + t * NN + n] = am;
        dsh[n] = (ad > 20.0f) ? ad : log1pf(__expf(ad));  // softplus
    }
    __syncthreads();

    // cov[t] = V V^T + diag(d)  — overwrites the whole block (incl. stashed h)
    float* covp = out + COV_OFF + (size_t)t * HBLK;
    for (int p = tid; p < NN * NN; p += 256) {
        int n = p / NN, m = p - n * NN;
        const float* vn = Vs + n * (RR + 1);
        const float* vm = Vs + m * (RR + 1);
        float acc = (n == m) ? dsh[n] : 0.0f;
#pragma unroll
        for (int r = 0; r < RR; ++r) acc = fmaf(vn[r], vm[r], acc);
        covp[p] = acc;
    }
}

extern "C" void kernel_launch(void* const* d_in, const int* in_sizes, int n_in,
                              void* d_out, int out_size, void* d_ws, size_t ws_size,
                              hipStream_t stream) {
    const float* inputs  = (const float*)d_in[0];
    const int*   indices = (const int*)d_in[1];
    const float* embW    = (const float*)d_in[2];
    const float* Wih0    = (const float*)d_in[3];
    const float* Whh0    = (const float*)d_in[4];
    const float* bih0    = (const float*)d_in[5];
    const float* bhh0    = (const float*)d_in[6];
    const float* Wih1    = (const float*)d_in[7];
    const float* Whh1    = (const float*)d_in[8];
    const float* bih1    = (const float*)d_in[9];
    const float* bhh1    = (const float*)d_in[10];
    const float* Wm      = (const float*)d_in[11];
    const float* bm      = (const float*)d_in[12];
    const float* Wv      = (const float*)d_in[13];
    const float* bv      = (const float*)d_in[14];
    const float* Wd      = (const float*)d_in[15];
    const float* bd      = (const float*)d_in[16];
    float* out = (float*)d_out;

    lstm_kernel<<<NN, 768, 0, stream>>>(inputs, Wih0, Whh0, bih0, bhh0,
                                        Wih1, Whh1, bih1, bhh1, out);
    head_kernel<<<TT, 256, 0, stream>>>(embW, indices, Wm, bm, Wv, bv, Wd, bd, out);
}

// Round 4
// 476.773 us; speedup vs baseline: 2.0629x; 2.0629x over previous
//
#include <hip/hip_runtime.h>
#include <hip/hip_bf16.h>
#include <math.h>

#define TT 512
#define NN 200
#define HH 64
#define EE 16
#define RR 10
#define MU_OFF 0
#define COV_OFF (TT*NN)      // 102400
#define HBLK (NN*NN)         // 40000 floats per t-block of cov
#define HPAD 68              // padded hist row

__device__ __forceinline__ float sigmoidf_(float x) {
    return 1.0f / (1.0f + __expf(-x));
}
__device__ __forceinline__ float tanhf_(float x) {
    x = fminf(15.0f, fmaxf(-15.0f, x));
    float e = __expf(2.0f * x);
    return (e - 1.0f) / (e + 1.0f);
}

// Raw wave-counted barrier: waits LDS only (lgkmcnt), never drains vmcnt,
// so the periodic global flush stores float across ticks.
#define BAR() do { asm volatile("s_waitcnt lgkmcnt(0)" ::: "memory"); \
                   __builtin_amdgcn_s_barrier();                      \
                   asm volatile("" ::: "memory"); } while (0)

// ---------------- Kernel A: 2-layer LSTM, layer-pipelined, 1 WG per batch ---
// Waves 0-3: layer0 gate rows (step t).  Waves 4-7: layer1 gate rows (step t-1).
// 2 barriers per tick, 513 ticks.
// amdgpu_waves_per_eu(2,2): cap the allocator's occupancy target at exactly
// the 2 waves/SIMD this 8-wave block needs -> 256-VGPR budget -> branch B's
// 128 weight floats stay in registers (R2/R3 spilled them to scratch because
// the default allocator chases 8 waves/SIMD = 64 VGPRs).
__global__
__attribute__((amdgpu_flat_work_group_size(512, 512), amdgpu_waves_per_eu(2, 2)))
void lstm_kernel(
    const float* __restrict__ inputs,
    const float* __restrict__ Wih0, const float* __restrict__ Whh0,
    const float* __restrict__ bih0, const float* __restrict__ bhh0,
    const float* __restrict__ Wih1, const float* __restrict__ Whh1,
    const float* __restrict__ bih1, const float* __restrict__ bhh1,
    float* __restrict__ out)
{
    const int n = blockIdx.x;
    const int tid = threadIdx.x;

    __shared__ float xs[TT];
    __shared__ float h0s[HH];
    __shared__ float h1s[HH];
    __shared__ float ga0[256];          // activated layer0 gates
    __shared__ float ga1[256];          // activated layer1 gates
    __shared__ float hist[64][HPAD];    // h1 history, flushed every 64 ticks

    xs[tid] = inputs[tid * NN + n];
    if (tid < HH) { h0s[tid] = 0.0f; h1s[tid] = 0.0f; }

    float* covbase = out + COV_OFF + n * HH;

    if (tid < 256) {
        // ================= layer-0 branch (waves 0-3) =================
        float w0[HH];
        {
            const float4* p0 = (const float4*)(Whh0 + tid * HH);
#pragma unroll
            for (int q = 0; q < 16; ++q) {
                float4 a = p0[q];
                w0[4*q+0] = a.x; w0[4*q+1] = a.y; w0[4*q+2] = a.z; w0[4*q+3] = a.w;
            }
        }
        const float wx = Wih0[tid];
        const float b0 = bih0[tid] + bhh0[tid];
        const bool  upd = (tid < HH);          // wave 0 updates c0/h0
        const int   gate = tid >> 6;           // wave-uniform
        float c0 = 0.0f;

        BAR();  // init barrier

        for (int t = 0; t <= TT; ++t) {
            if (t < TT) {
                float a0 = fmaf(wx, xs[t], b0), a1 = 0.f, a2 = 0.f, a3 = 0.f;
                const float4* h4 = (const float4*)h0s;
#pragma unroll
                for (int q = 0; q < 16; ++q) {
                    float4 h = h4[q];
                    a0 = fmaf(w0[4*q+0], h.x, a0);
                    a1 = fmaf(w0[4*q+1], h.y, a1);
                    a2 = fmaf(w0[4*q+2], h.z, a2);
                    a3 = fmaf(w0[4*q+3], h.w, a3);
                }
                float g = (a0 + a1) + (a2 + a3);
                ga0[tid] = (gate == 2) ? tanhf_(g) : sigmoidf_(g);
            }
            BAR();
            if (t < TT && upd) {
                float ia = ga0[tid], fa = ga0[tid + 64];
                float gg = ga0[tid + 128], oa = ga0[tid + 192];
                c0 = fmaf(fa, c0, ia * gg);
                h0s[tid] = oa * tanhf_(c0);
            }
            BAR();
            if ((t & 63) == 0 && t > 0) {   // flush steps t-64..t-1
                const int s = tid >> 3;
                const int c = (tid & 7) * 8;
                float4 v0 = *(const float4*)&hist[s][c];
                float4 v1 = *(const float4*)&hist[s][c + 4];
                float* dst = covbase + (size_t)(t - 64 + s) * HBLK + c;
                ((float4*)dst)[0] = v0;
                ((float4*)dst)[1] = v1;
            }
        }
    } else {
        // ================= layer-1 branch (waves 4-7) =================
        const int r = tid - 256;
        float wi1[HH], wh1[HH];
        {
            const float4* pi = (const float4*)(Wih1 + r * HH);
            const float4* ph = (const float4*)(Whh1 + r * HH);
#pragma unroll
            for (int q = 0; q < 16; ++q) {
                float4 b = pi[q];
                wi1[4*q+0] = b.x; wi1[4*q+1] = b.y; wi1[4*q+2] = b.z; wi1[4*q+3] = b.w;
                float4 c = ph[q];
                wh1[4*q+0] = c.x; wh1[4*q+1] = c.y; wh1[4*q+2] = c.z; wh1[4*q+3] = c.w;
            }
        }
        const float b1 = bih1[r] + bhh1[r];
        const bool  upd = (r < HH);            // wave 4 updates c1/h1
        const int   gate = r >> 6;             // wave-uniform
        float c1 = 0.0f;

        BAR();  // init barrier

        for (int t = 0; t <= TT; ++t) {
            if (t >= 1) {
                // layer1 for step t-1: inputs h0[t-1] (current h0s), h1[t-2] (current h1s)
                float a0 = b1, a1 = 0.f, a2 = 0.f, a3 = 0.f;
                float s0 = 0.f, s1 = 0.f, s2 = 0.f, s3 = 0.f;
                const float4* ha = (const float4*)h0s;
                const float4* hb = (const float4*)h1s;
#pragma unroll
                for (int q = 0; q < 16; ++q) {
                    float4 x = ha[q];
                    float4 y = hb[q];
                    a0 = fmaf(wi1[4*q+0], x.x, a0);
                    a1 = fmaf(wi1[4*q+1], x.y, a1);
                    a2 = fmaf(wi1[4*q+2], x.z, a2);
                    a3 = fmaf(wi1[4*q+3], x.w, a3);
                    s0 = fmaf(wh1[4*q+0], y.x, s0);
                    s1 = fmaf(wh1[4*q+1], y.y, s1);
                    s2 = fmaf(wh1[4*q+2], y.z, s2);
                    s3 = fmaf(wh1[4*q+3], y.w, s3);
                }
                float g = ((a0 + a1) + (a2 + a3)) + ((s0 + s1) + (s2 + s3));
                ga1[r] = (gate == 2) ? tanhf_(g) : sigmoidf_(g);
            }
            BAR();
            if (t >= 1 && upd) {
                float ia = ga1[r], fa = ga1[r + 64];
                float gg = ga1[r + 128], oa = ga1[r + 192];
                c1 = fmaf(fa, c1, ia * gg);
                float h1 = oa * tanhf_(c1);
                h1s[r] = h1;
                hist[(t - 1) & 63][r] = h1;
            }
            BAR();
            if ((t & 63) == 0 && t > 0) {   // flush steps t-64..t-1 (same code as branch A)
                const int s = tid >> 3;
                const int c = (tid & 7) * 8;
                float4 v0 = *(const float4*)&hist[s][c];
                float4 v1 = *(const float4*)&hist[s][c + 4];
                float* dst = covbase + (size_t)(t - 64 + s) * HBLK + c;
                ((float4*)dst)[0] = v0;
                ((float4*)dst)[1] = v1;
            }
        }
    }
}

// ---------------- Kernel B: heads + covariance, one workgroup per t ----------
__global__ __launch_bounds__(256) void head_kernel(
    const float* __restrict__ embW, const int* __restrict__ indices,
    const float* __restrict__ Wm, const float* __restrict__ bm,
    const float* __restrict__ Wv, const float* __restrict__ bv,
    const float* __restrict__ Wd, const float* __restrict__ bd,
    float* __restrict__ out)
{
    const int t = blockIdx.x;
    const int tid = threadIdx.x;

    __shared__ float hs[NN * HH];          // 12800
    __shared__ float embs[NN * EE];        // 3200
    __shared__ float Wvs[(HH + EE) * RR];  // 800
    __shared__ float Wms[HH + EE];
    __shared__ float Wds[HH + EE];
    __shared__ float Vs[NN * (RR + 1)];    // stride 11 to dodge bank conflicts
    __shared__ float dsh[NN];
    __shared__ float bvs[RR];

    const float* hsrc = out + COV_OFF + (size_t)t * HBLK;
    for (int i = tid; i < (NN * HH) / 4; i += 256)
        ((float4*)hs)[i] = ((const float4*)hsrc)[i];
    for (int i = tid; i < NN * EE; i += 256) {
        int n = i >> 4, e = i & 15;
        embs[i] = embW[indices[n] * EE + e];
    }
    for (int i = tid; i < (HH + EE) * RR; i += 256) Wvs[i] = Wv[i];
    if (tid < HH + EE) { Wms[tid] = Wm[tid]; Wds[tid] = Wd[tid]; }
    if (tid < RR) bvs[tid] = bv[tid];
    __syncthreads();

    // V = y @ Wv + bv
    for (int p = tid; p < NN * RR; p += 256) {
        int n = p / RR, r = p - n * RR;
        const float* hn = hs + n * HH;
        const float* en = embs + n * EE;
        float acc = bvs[r];
#pragma unroll 8
        for (int k = 0; k < HH; ++k) acc = fmaf(hn[k], Wvs[k * RR + r], acc);
#pragma unroll
        for (int k = 0; k < EE; ++k) acc = fmaf(en[k], Wvs[(HH + k) * RR + r], acc);
        Vs[n * (RR + 1) + r] = acc;
    }
    // mu and d
    const float bmv = bm[0], bdv = bd[0];
    for (int n = tid; n < NN; n += 256) {
        const float* hn = hs + n * HH;
        const float* en = embs + n * EE;
        float am = bmv, ad = bdv;
#pragma unroll 8
        for (int k = 0; k < HH; ++k) {
            float h = hn[k];
            am = fmaf(h, Wms[k], am);
            ad = fmaf(h, Wds[k], ad);
        }
#pragma unroll
        for (int k = 0; k < EE; ++k) {
            float e = en[k];
            am = fmaf(e, Wms[HH + k], am);
            ad = fmaf(e, Wds[HH + k], ad);
        }
        out[MU_OFF + t * NN + n] = am;
        dsh[n] = (ad > 20.0f) ? ad : log1pf(__expf(ad));  // softplus
    }
    __syncthreads();

    // cov[t] = V V^T + diag(d)  — overwrites the whole block (incl. stashed h)
    float* covp = out + COV_OFF + (size_t)t * HBLK;
    for (int p = tid; p < NN * NN; p += 256) {
        int n = p / NN, m = p - n * NN;
        const float* vn = Vs + n * (RR + 1);
        const float* vm = Vs + m * (RR + 1);
        float acc = (n == m) ? dsh[n] : 0.0f;
#pragma unroll
        for (int r = 0; r < RR; ++r) acc = fmaf(vn[r], vm[r], acc);
        covp[p] = acc;
    }
}

extern "C" void kernel_launch(void* const* d_in, const int* in_sizes, int n_in,
                              void* d_out, int out_size, void* d_ws, size_t ws_size,
                              hipStream_t stream) {
    const float* inputs  = (const float*)d_in[0];
    const int*   indices = (const int*)d_in[1];
    const float* embW    = (const float*)d_in[2];
    const float* Wih0    = (const float*)d_in[3];
    const float* Whh0    = (const float*)d_in[4];
    const float* bih0    = (const float*)d_in[5];
    const float* bhh0    = (const float*)d_in[6];
    const float* Wih1    = (const float*)d_in[7];
    const float* Whh1    = (const float*)d_in[8];
    const float* bih1    = (const float*)d_in[9];
    const float* bhh1    = (const float*)d_in[10];
    const float* Wm      = (const float*)d_in[11];
    const float* bm      = (const float*)d_in[12];
    const float* Wv      = (const float*)d_in[13];
    const float* bv      = (const float*)d_in[14];
    const float* Wd      = (const float*)d_in[15];
    const float* bd      = (const float*)d_in[16];
    float* out = (float*)d_out;

    lstm_kernel<<<NN, 512, 0, stream>>>(inputs, Wih0, Whh0, bih0, bhh0,
                                        Wih1, Whh1, bih1, bhh1, out);
    head_kernel<<<TT, 256, 0, stream>>>(embW, indices, Wm, bm, Wv, bv, Wd, bd, out);
}

// Round 5
// 475.756 us; speedup vs baseline: 2.0673x; 1.0021x over previous
//
#include <hip/hip_runtime.h>
#include <hip/hip_bf16.h>
#include <math.h>

#define TT 512
#define NN 200
#define HH 64
#define EE 16
#define RR 10
#define MU_OFF 0
#define COV_OFF (TT*NN)      // 102400
#define HBLK (NN*NN)         // 40000 floats per t-block of cov
#define HPAD 68              // padded hist row

__device__ __forceinline__ float sigmoidf_(float x) {
    return 1.0f / (1.0f + __expf(-x));
}
__device__ __forceinline__ float tanhf_(float x) {
    x = fminf(15.0f, fmaxf(-15.0f, x));
    float e = __expf(2.0f * x);
    return (e - 1.0f) / (e + 1.0f);
}

// Raw wave-counted barrier: waits LDS only (lgkmcnt), never drains vmcnt,
// so the periodic global flush stores float across ticks.
#define BAR() do { asm volatile("s_waitcnt lgkmcnt(0)" ::: "memory"); \
                   __builtin_amdgcn_s_barrier();                      \
                   asm volatile("" ::: "memory"); } while (0)

// Apply macro M for q = 0..15
#define RQ(M) M(0) M(1) M(2) M(3) M(4) M(5) M(6) M(7) \
              M(8) M(9) M(10) M(11) M(12) M(13) M(14) M(15)

// ---------------- Kernel A: 2-layer LSTM, layer-pipelined, 1 WG per batch ---
// Waves 0-3: layer0 gate rows (step t).  Waves 4-7: layer1 gate rows (step t-1).
// Weights held as NAMED float4 scalars (not arrays) so SROA must promote them
// to VGPRs — R2/R4 kept them as allocas (VGPR_Count 84/88 despite a 256-VGPR
// budget from waves_per_eu(2,2)) and re-read them every tick.
__global__
__attribute__((amdgpu_flat_work_group_size(512, 512), amdgpu_waves_per_eu(2, 2)))
void lstm_kernel(
    const float* __restrict__ inputs,
    const float* __restrict__ Wih0, const float* __restrict__ Whh0,
    const float* __restrict__ bih0, const float* __restrict__ bhh0,
    const float* __restrict__ Wih1, const float* __restrict__ Whh1,
    const float* __restrict__ bih1, const float* __restrict__ bhh1,
    float* __restrict__ out)
{
    const int n = blockIdx.x;
    const int tid = threadIdx.x;

    __shared__ float xs[TT];
    __shared__ float h0s[HH];
    __shared__ float h1s[HH];
    __shared__ float ga0[256];          // activated layer0 gates
    __shared__ float ga1[256];          // activated layer1 gates
    __shared__ float hist[64][HPAD];    // h1 history, flushed every 64 ticks

    xs[tid] = inputs[tid * NN + n];
    if (tid < HH) { h0s[tid] = 0.0f; h1s[tid] = 0.0f; }

    float* covbase = out + COV_OFF + n * HH;

    if (tid < 256) {
        // ================= layer-0 branch (waves 0-3) =================
        const float4* p0 = (const float4*)(Whh0 + tid * HH);
#define DECLA(q) float4 wA##q = p0[q];
        RQ(DECLA)
        const float wx = Wih0[tid];
        const float b0 = bih0[tid] + bhh0[tid];
        const bool  upd = (tid < HH);          // wave 0 updates c0/h0
        const int   gate = tid >> 6;           // wave-uniform
        float c0 = 0.0f;

        BAR();  // init barrier

        for (int t = 0; t <= TT; ++t) {
            if (t < TT) {
                float a0 = fmaf(wx, xs[t], b0), a1 = 0.f, a2 = 0.f, a3 = 0.f;
                const float4* h4 = (const float4*)h0s;
#define FMAA(q) { float4 h = h4[q];                  \
                  a0 = fmaf(wA##q.x, h.x, a0);       \
                  a1 = fmaf(wA##q.y, h.y, a1);       \
                  a2 = fmaf(wA##q.z, h.z, a2);       \
                  a3 = fmaf(wA##q.w, h.w, a3); }
                RQ(FMAA)
                float g = (a0 + a1) + (a2 + a3);
                ga0[tid] = (gate == 2) ? tanhf_(g) : sigmoidf_(g);
            }
            BAR();
            if (t < TT && upd) {
                float ia = ga0[tid], fa = ga0[tid + 64];
                float gg = ga0[tid + 128], oa = ga0[tid + 192];
                c0 = fmaf(fa, c0, ia * gg);
                h0s[tid] = oa * tanhf_(c0);
            }
            BAR();
            if ((t & 63) == 0 && t > 0) {   // flush steps t-64..t-1
                const int s = tid >> 3;
                const int c = (tid & 7) * 8;
                float4 v0 = *(const float4*)&hist[s][c];
                float4 v1 = *(const float4*)&hist[s][c + 4];
                float* dst = covbase + (size_t)(t - 64 + s) * HBLK + c;
                ((float4*)dst)[0] = v0;
                ((float4*)dst)[1] = v1;
            }
        }
    } else {
        // ================= layer-1 branch (waves 4-7) =================
        const int r = tid - 256;
        const float4* pi = (const float4*)(Wih1 + r * HH);
        const float4* ph = (const float4*)(Whh1 + r * HH);
#define DECLB(q) float4 wI##q = pi[q]; float4 wH##q = ph[q];
        RQ(DECLB)
        const float b1 = bih1[r] + bhh1[r];
        const bool  upd = (r < HH);            // wave 4 updates c1/h1
        const int   gate = r >> 6;             // wave-uniform
        float c1 = 0.0f;

        BAR();  // init barrier

        for (int t = 0; t <= TT; ++t) {
            if (t >= 1) {
                // layer1 for step t-1: inputs h0[t-1] (current h0s), h1[t-2] (current h1s)
                float a0 = b1, a1 = 0.f, a2 = 0.f, a3 = 0.f;
                float s0 = 0.f, s1 = 0.f, s2 = 0.f, s3 = 0.f;
                const float4* ha = (const float4*)h0s;
                const float4* hb = (const float4*)h1s;
#define FMAB(q) { float4 x = ha[q]; float4 y = hb[q]; \
                  a0 = fmaf(wI##q.x, x.x, a0);        \
                  a1 = fmaf(wI##q.y, x.y, a1);        \
                  a2 = fmaf(wI##q.z, x.z, a2);        \
                  a3 = fmaf(wI##q.w, x.w, a3);        \
                  s0 = fmaf(wH##q.x, y.x, s0);        \
                  s1 = fmaf(wH##q.y, y.y, s1);        \
                  s2 = fmaf(wH##q.z, y.z, s2);        \
                  s3 = fmaf(wH##q.w, y.w, s3); }
                RQ(FMAB)
                float g = ((a0 + a1) + (a2 + a3)) + ((s0 + s1) + (s2 + s3));
                ga1[r] = (gate == 2) ? tanhf_(g) : sigmoidf_(g);
            }
            BAR();
            if (t >= 1 && upd) {
                float ia = ga1[r], fa = ga1[r + 64];
                float gg = ga1[r + 128], oa = ga1[r + 192];
                c1 = fmaf(fa, c1, ia * gg);
                float h1 = oa * tanhf_(c1);
                h1s[r] = h1;
                hist[(t - 1) & 63][r] = h1;
            }
            BAR();
            if ((t & 63) == 0 && t > 0) {   // flush steps t-64..t-1
                const int s = tid >> 3;
                const int c = (tid & 7) * 8;
                float4 v0 = *(const float4*)&hist[s][c];
                float4 v1 = *(const float4*)&hist[s][c + 4];
                float* dst = covbase + (size_t)(t - 64 + s) * HBLK + c;
                ((float4*)dst)[0] = v0;
                ((float4*)dst)[1] = v1;
            }
        }
    }
}

// ---------------- Kernel B: heads + covariance, one workgroup per t ----------
__global__ __launch_bounds__(256) void head_kernel(
    const float* __restrict__ embW, const int* __restrict__ indices,
    const float* __restrict__ Wm, const float* __restrict__ bm,
    const float* __restrict__ Wv, const float* __restrict__ bv,
    const float* __restrict__ Wd, const float* __restrict__ bd,
    float* __restrict__ out)
{
    const int t = blockIdx.x;
    const int tid = threadIdx.x;

    __shared__ float hs[NN * HH];          // 12800
    __shared__ float embs[NN * EE];        // 3200
    __shared__ float Wvs[(HH + EE) * RR];  // 800
    __shared__ float Wms[HH + EE];
    __shared__ float Wds[HH + EE];
    __shared__ float Vs[NN * (RR + 1)];    // stride 11 to dodge bank conflicts
    __shared__ float dsh[NN];
    __shared__ float bvs[RR];

    const float* hsrc = out + COV_OFF + (size_t)t * HBLK;
    for (int i = tid; i < (NN * HH) / 4; i += 256)
        ((float4*)hs)[i] = ((const float4*)hsrc)[i];
    for (int i = tid; i < NN * EE; i += 256) {
        int n = i >> 4, e = i & 15;
        embs[i] = embW[indices[n] * EE + e];
    }
    for (int i = tid; i < (HH + EE) * RR; i += 256) Wvs[i] = Wv[i];
    if (tid < HH + EE) { Wms[tid] = Wm[tid]; Wds[tid] = Wd[tid]; }
    if (tid < RR) bvs[tid] = bv[tid];
    __syncthreads();

    // V = y @ Wv + bv
    for (int p = tid; p < NN * RR; p += 256) {
        int n = p / RR, r = p - n * RR;
        const float* hn = hs + n * HH;
        const float* en = embs + n * EE;
        float acc = bvs[r];
#pragma unroll 8
        for (int k = 0; k < HH; ++k) acc = fmaf(hn[k], Wvs[k * RR + r], acc);
#pragma unroll
        for (int k = 0; k < EE; ++k) acc = fmaf(en[k], Wvs[(HH + k) * RR + r], acc);
        Vs[n * (RR + 1) + r] = acc;
    }
    // mu and d
    const float bmv = bm[0], bdv = bd[0];
    for (int n = tid; n < NN; n += 256) {
        const float* hn = hs + n * HH;
        const float* en = embs + n * EE;
        float am = bmv, ad = bdv;
#pragma unroll 8
        for (int k = 0; k < HH; ++k) {
            float h = hn[k];
            am = fmaf(h, Wms[k], am);
            ad = fmaf(h, Wds[k], ad);
        }
#pragma unroll
        for (int k = 0; k < EE; ++k) {
            float e = en[k];
            am = fmaf(e, Wms[HH + k], am);
            ad = fmaf(e, Wds[HH + k], ad);
        }
        out[MU_OFF + t * NN + n] = am;
        dsh[n] = (ad > 20.0f) ? ad : log1pf(__expf(ad));  // softplus
    }
    __syncthreads();

    // cov[t] = V V^T + diag(d)  — overwrites the whole block (incl. stashed h)
    float* covp = out + COV_OFF + (size_t)t * HBLK;
    for (int p = tid; p < NN * NN; p += 256) {
        int n = p / NN, m = p - n * NN;
        const float* vn = Vs + n * (RR + 1);
        const float* vm = Vs + m * (RR + 1);
        float acc = (n == m) ? dsh[n] : 0.0f;
#pragma unroll
        for (int r = 0; r < RR; ++r) acc = fmaf(vn[r], vm[r], acc);
        covp[p] = acc;
    }
}

extern "C" void kernel_launch(void* const* d_in, const int* in_sizes, int n_in,
                              void* d_out, int out_size, void* d_ws, size_t ws_size,
                              hipStream_t stream) {
    const float* inputs  = (const float*)d_in[0];
    const int*   indices = (const int*)d_in[1];
    const float* embW    = (const float*)d_in[2];
    const float* Wih0    = (const float*)d_in[3];
    const float* Whh0    = (const float*)d_in[4];
    const float* bih0    = (const float*)d_in[5];
    const float* bhh0    = (const float*)d_in[6];
    const float* Wih1    = (const float*)d_in[7];
    const float* Whh1    = (const float*)d_in[8];
    const float* bih1    = (const float*)d_in[9];
    const float* bhh1    = (const float*)d_in[10];
    const float* Wm      = (const float*)d_in[11];
    const float* bm      = (const float*)d_in[12];
    const float* Wv      = (const float*)d_in[13];
    const float* bv      = (const float*)d_in[14];
    const float* Wd      = (const float*)d_in[15];
    const float* bd      = (const float*)d_in[16];
    float* out = (float*)d_out;

    lstm_kernel<<<NN, 512, 0, stream>>>(inputs, Wih0, Whh0, bih0, bhh0,
                                        Wih1, Whh1, bih1, bhh1, out);
    head_kernel<<<TT, 256, 0, stream>>>(embW, indices, Wm, bm, Wv, bv, Wd, bd, out);
}